// Round 1
// baseline (217.547 us; speedup 1.0000x reference)
//
#include <hip/hip_runtime.h>
#include <math.h>

// GRU: B=65536, T=9, I=57, H=2, O=1.
// One thread per batch element; 64-thread (single-wave) blocks; per-timestep
// x-tiles staged into LDS via async global_load_lds (lane-contiguous 256B per
// instruction), double-buffered.

#define T_STEPS 9
#define I_DIM   57
#define ROW_F   513           // T*I floats per batch element
#define TILE_F  (64 * I_DIM)  // 3648 floats per tile buffer

__device__ __forceinline__ float sigm(float x) {
    return 1.0f / (1.0f + __expf(-x));
}
__device__ __forceinline__ float tanh_fast(float x) {
    x = fminf(fmaxf(x, -15.0f), 15.0f);
    float e = __expf(2.0f * x);
    return (e - 1.0f) / (e + 1.0f);
}

__global__ __launch_bounds__(64, 2) void gru_kernel(
    const float* __restrict__ x,    // [B, T, I]
    const float* __restrict__ Wih,  // [6, 57]
    const float* __restrict__ Whh,  // [6, 2]
    const float* __restrict__ bih,  // [6]
    const float* __restrict__ bhh,  // [6]
    const float* __restrict__ fcw,  // [1, 2]
    const float* __restrict__ fcb,  // [1]
    float* __restrict__ out)        // [B, 1]
{
    __shared__ float tile[2][TILE_F];
    const int lane = threadIdx.x;
    const int blk  = blockIdx.x;
    const char* xblk = (const char*)(x + (size_t)blk * 64 * ROW_F);

    // Per-lane byte offsets (row*2052 + col*4) for the 57 staging loads:
    // flat f = lane + 64*k over the block's contiguous 64*513-float region,
    // row = f/57, col = f%57, computed incrementally (f += 64 => col += 7 with
    // row += 1, carry row += 1 more when col wraps). No integer division.
    int offB[I_DIM];
    {
        int row = (lane >= I_DIM) ? 1 : 0;
        int col = lane - row * I_DIM;
#pragma unroll
        for (int k = 0; k < I_DIM; ++k) {
            offB[k] = row * (ROW_F * 4) + col * 4;
            int c2 = col + 7;
            if (c2 >= I_DIM) { row += 2; col = c2 - I_DIM; }
            else             { row += 1; col = c2; }
        }
    }

    // Async-stage timestep t's 64x57 tile into tile[buf].
    // LDS dest per instruction k is wave-uniform (&tile[buf][64*k]); HW adds
    // lane*4, matching our f = lane + 64*k layout exactly.
    auto issue_tile = [&](int t, int buf) {
        const char* base = xblk + t * (I_DIM * 4);
#pragma unroll
        for (int k = 0; k < I_DIM; ++k) {
            __builtin_amdgcn_global_load_lds(
                (const __attribute__((address_space(1))) void*)(base + offB[k]),
                (__attribute__((address_space(3))) void*)(&tile[buf][64 * k]),
                4, 0, 0);
        }
    };

    issue_tile(0, 0);

    // Small uniform weights -> SGPRs.
    const float b0 = bih[0], b1 = bih[1], b2 = bih[2],
                b3 = bih[3], b4 = bih[4], b5 = bih[5];
    const float c0 = bhh[0], c1 = bhh[1], c2 = bhh[2],
                c3 = bhh[3], c4 = bhh[4], c5 = bhh[5];
    const float w00 = Whh[0],  w01 = Whh[1];   // gate r0
    const float w10 = Whh[2],  w11 = Whh[3];   // gate r1
    const float w20 = Whh[4],  w21 = Whh[5];   // gate z0
    const float w30 = Whh[6],  w31 = Whh[7];   // gate z1
    const float w40 = Whh[8],  w41 = Whh[9];   // gate n0
    const float w50 = Whh[10], w51 = Whh[11];  // gate n1

    float h0 = 0.0f, h1 = 0.0f;

    for (int t = 0; t < T_STEPS; ++t) {
        __syncthreads();                       // tile[t&1] loads complete
        if (t + 1 < T_STEPS) issue_tile(t + 1, (t + 1) & 1);  // prefetch

        const float* rowp = &tile[t & 1][lane * I_DIM];
        float a0 = b0, a1 = b1, a2 = b2, a3 = b3, a4 = b4, a5 = b5;
#pragma unroll
        for (int i = 0; i < I_DIM; ++i) {
            float xv = rowp[i];
            a0 = fmaf(xv, Wih[0 * I_DIM + i], a0);
            a1 = fmaf(xv, Wih[1 * I_DIM + i], a1);
            a2 = fmaf(xv, Wih[2 * I_DIM + i], a2);
            a3 = fmaf(xv, Wih[3 * I_DIM + i], a3);
            a4 = fmaf(xv, Wih[4 * I_DIM + i], a4);
            a5 = fmaf(xv, Wih[5 * I_DIM + i], a5);
        }
        // hidden-side gate projections
        const float g0 = c0 + w00 * h0 + w01 * h1;
        const float g1 = c1 + w10 * h0 + w11 * h1;
        const float g2 = c2 + w20 * h0 + w21 * h1;
        const float g3 = c3 + w30 * h0 + w31 * h1;
        const float g4 = c4 + w40 * h0 + w41 * h1;
        const float g5 = c5 + w50 * h0 + w51 * h1;

        const float r0 = sigm(a0 + g0);
        const float r1 = sigm(a1 + g1);
        const float z0 = sigm(a2 + g2);
        const float z1 = sigm(a3 + g3);
        const float n0 = tanh_fast(a4 + r0 * g4);
        const float n1 = tanh_fast(a5 + r1 * g5);
        h0 = (1.0f - z0) * n0 + z0 * h0;
        h1 = (1.0f - z1) * n1 + z1 * h1;
    }

    out[blk * 64 + lane] = fcw[0] * h0 + fcw[1] * h1 + fcb[0];
}

extern "C" void kernel_launch(void* const* d_in, const int* in_sizes, int n_in,
                              void* d_out, int out_size, void* d_ws, size_t ws_size,
                              hipStream_t stream) {
    const float* x   = (const float*)d_in[0];
    const float* Wih = (const float*)d_in[1];
    const float* Whh = (const float*)d_in[2];
    const float* bih = (const float*)d_in[3];
    const float* bhh = (const float*)d_in[4];
    const float* fcw = (const float*)d_in[5];
    const float* fcb = (const float*)d_in[6];
    float* out = (float*)d_out;

    gru_kernel<<<dim3(1024), dim3(64), 0, stream>>>(
        x, Wih, Whh, bih, bhh, fcw, fcb, out);
}

// Round 2
// 212.708 us; speedup vs baseline: 1.0227x; 1.0227x over previous
//
#include <hip/hip_runtime.h>
#include <math.h>

// GRU: B=65536, T=9, I=57, H=2, O=1.
// One thread per batch element; 64-thread (single-wave) blocks; per-timestep
// x-tiles staged into LDS via async global_load_lds (lane-contiguous 256B per
// instruction), double-buffered.
//
// R2 change vs R1: compute loop restructured gate-outer / i-inner with the
// x-row cached in 57 VGPRs and `#pragma unroll 1` on the t-loop. R1's
// i-outer/g-inner unrolled form needed all 342 Wih uniforms live at once ->
// SGPR/VGPR overflow -> serialized weight reloads (~3078 loads x ~170cyc
// ~= 520k cyc = the observed 217us). Gate-outer caps live weights at <=57.

#define T_STEPS 9
#define I_DIM   57
#define ROW_F   513           // T*I floats per batch element
#define TILE_F  (64 * I_DIM)  // 3648 floats per tile buffer

__device__ __forceinline__ float sigm(float x) {
    return 1.0f / (1.0f + __expf(-x));
}
__device__ __forceinline__ float tanh_fast(float x) {
    x = fminf(fmaxf(x, -15.0f), 15.0f);
    float e = __expf(2.0f * x);
    return (e - 1.0f) / (e + 1.0f);
}

__global__ __launch_bounds__(64, 2) void gru_kernel(
    const float* __restrict__ x,    // [B, T, I]
    const float* __restrict__ Wih,  // [6, 57]
    const float* __restrict__ Whh,  // [6, 2]
    const float* __restrict__ bih,  // [6]
    const float* __restrict__ bhh,  // [6]
    const float* __restrict__ fcw,  // [1, 2]
    const float* __restrict__ fcb,  // [1]
    float* __restrict__ out)        // [B, 1]
{
    __shared__ float tile[2][TILE_F];
    const int lane = threadIdx.x;
    const int blk  = blockIdx.x;
    const char* xblk = (const char*)(x + (size_t)blk * 64 * ROW_F);

    // Per-lane byte offsets (row*2052 + col*4) for the 57 staging loads:
    // flat f = lane + 64*k over the block's contiguous 64*513-float region,
    // row = f/57, col = f%57, computed incrementally. No integer division.
    int offB[I_DIM];
    {
        int row = (lane >= I_DIM) ? 1 : 0;
        int col = lane - row * I_DIM;
#pragma unroll
        for (int k = 0; k < I_DIM; ++k) {
            offB[k] = row * (ROW_F * 4) + col * 4;
            int c2 = col + 7;
            if (c2 >= I_DIM) { row += 2; col = c2 - I_DIM; }
            else             { row += 1; col = c2; }
        }
    }

    // Async-stage timestep t's 64x57 tile into tile[buf].
    // LDS dest per instruction k is wave-uniform (&tile[buf][64*k]); HW adds
    // lane*4, matching our f = lane + 64*k layout exactly.
    auto issue_tile = [&](int t, int buf) {
        const char* base = xblk + t * (I_DIM * 4);
#pragma unroll
        for (int k = 0; k < I_DIM; ++k) {
            __builtin_amdgcn_global_load_lds(
                (const __attribute__((address_space(1))) void*)(base + offB[k]),
                (__attribute__((address_space(3))) void*)(&tile[buf][64 * k]),
                4, 0, 0);
        }
    };

    issue_tile(0, 0);

    // Small uniform params -> SGPRs (6+6+12+3 = manageable).
    const float b0 = bih[0], b1 = bih[1], b2 = bih[2],
                b3 = bih[3], b4 = bih[4], b5 = bih[5];
    const float c0 = bhh[0], c1 = bhh[1], c2 = bhh[2],
                c3 = bhh[3], c4 = bhh[4], c5 = bhh[5];
    const float w00 = Whh[0],  w01 = Whh[1];   // gate r0
    const float w10 = Whh[2],  w11 = Whh[3];   // gate r1
    const float w20 = Whh[4],  w21 = Whh[5];   // gate z0
    const float w30 = Whh[6],  w31 = Whh[7];   // gate z1
    const float w40 = Whh[8],  w41 = Whh[9];   // gate n0
    const float w50 = Whh[10], w51 = Whh[11];  // gate n1

    float h0 = 0.0f, h1 = 0.0f;

#pragma unroll 1
    for (int t = 0; t < T_STEPS; ++t) {
        __syncthreads();                       // tile[t&1] loads complete
        if (t + 1 < T_STEPS) issue_tile(t + 1, (t + 1) & 1);  // prefetch

        // Cache this lane's x-row in VGPRs (57 ds_read_b32; stride 57 floats
        // is odd -> 2-way bank aliasing only = free).
        const float* rowp = &tile[t & 1][lane * I_DIM];
        float xr[I_DIM];
#pragma unroll
        for (int i = 0; i < I_DIM; ++i) xr[i] = rowp[i];

        // Gate-outer dot products: at most ~57 uniform Wih values live at a
        // time -> compiler can use batched s_load from the scalar cache.
        float a0 = b0, a1 = b1, a2 = b2, a3 = b3, a4 = b4, a5 = b5;
        {
            const float* wg = Wih + 0 * I_DIM;
#pragma unroll
            for (int i = 0; i < I_DIM; ++i) a0 = fmaf(xr[i], wg[i], a0);
        }
        {
            const float* wg = Wih + 1 * I_DIM;
#pragma unroll
            for (int i = 0; i < I_DIM; ++i) a1 = fmaf(xr[i], wg[i], a1);
        }
        {
            const float* wg = Wih + 2 * I_DIM;
#pragma unroll
            for (int i = 0; i < I_DIM; ++i) a2 = fmaf(xr[i], wg[i], a2);
        }
        {
            const float* wg = Wih + 3 * I_DIM;
#pragma unroll
            for (int i = 0; i < I_DIM; ++i) a3 = fmaf(xr[i], wg[i], a3);
        }
        {
            const float* wg = Wih + 4 * I_DIM;
#pragma unroll
            for (int i = 0; i < I_DIM; ++i) a4 = fmaf(xr[i], wg[i], a4);
        }
        {
            const float* wg = Wih + 5 * I_DIM;
#pragma unroll
            for (int i = 0; i < I_DIM; ++i) a5 = fmaf(xr[i], wg[i], a5);
        }

        // hidden-side gate projections
        const float g0 = c0 + w00 * h0 + w01 * h1;
        const float g1 = c1 + w10 * h0 + w11 * h1;
        const float g2 = c2 + w20 * h0 + w21 * h1;
        const float g3 = c3 + w30 * h0 + w31 * h1;
        const float g4 = c4 + w40 * h0 + w41 * h1;
        const float g5 = c5 + w50 * h0 + w51 * h1;

        const float r0 = sigm(a0 + g0);
        const float r1 = sigm(a1 + g1);
        const float z0 = sigm(a2 + g2);
        const float z1 = sigm(a3 + g3);
        const float n0 = tanh_fast(a4 + r0 * g4);
        const float n1 = tanh_fast(a5 + r1 * g5);
        h0 = (1.0f - z0) * n0 + z0 * h0;
        h1 = (1.0f - z1) * n1 + z1 * h1;
    }

    out[blk * 64 + lane] = fcw[0] * h0 + fcw[1] * h1 + fcb[0];
}

extern "C" void kernel_launch(void* const* d_in, const int* in_sizes, int n_in,
                              void* d_out, int out_size, void* d_ws, size_t ws_size,
                              hipStream_t stream) {
    const float* x   = (const float*)d_in[0];
    const float* Wih = (const float*)d_in[1];
    const float* Whh = (const float*)d_in[2];
    const float* bih = (const float*)d_in[3];
    const float* bhh = (const float*)d_in[4];
    const float* fcw = (const float*)d_in[5];
    const float* fcb = (const float*)d_in[6];
    float* out = (float*)d_out;

    gru_kernel<<<dim3(1024), dim3(64), 0, stream>>>(
        x, Wih, Whh, bih, bhh, fcw, fcb, out);
}